// Round 8
// baseline (94.666 us; speedup 1.0000x reference)
//
#include <hip/hip_runtime.h>

#define NBOX 4000
#define NPAD 4096
#define BATCH 8
#define WPR 64          // 64-bit words per suppression row
#define MAXK 300
#define NSB2 32         // 128-row superblocks

typedef unsigned long long u64;

// Static device scratch (deterministic: everything consulted is rewritten
// every call; rows >= nvalid are masked out before use).
__device__ u64 g_sup[BATCH][NPAD][WPR];            // ~16.8 MB full rows
__device__ u64 g_tileA[BATCH][NSB2 + 1][128];      // word 2s  of row s*128+r
__device__ u64 g_tileB[BATCH][NSB2 + 1][128];      // word 2s+1 of row s*128+r
__device__ float4 g_sorted[BATCH][NPAD];           // 512 KB
__device__ int g_nvalid[BATCH];

// ---------------------------------------------------------------------------
// Kernel 1: per-batch stable LSD radix sort (6 passes x 4 bits). (unchanged,
// proven bit-exact) Key k = 0x3F800000 - bits(fg): valid => fg > 0.5 => k in
// (0, 0x800000), fits 24 bits. Invalid/pad k = 0xFFFFFF sorts last. Stable
// blocked radix preserves original-index order for ties (jnp.argsort).
// ---------------------------------------------------------------------------
#define SORT_T 256
#define EPT 16
#define HP 264
#define KIDX(n) ((((n) >> 4) * 17) + ((n) & 15))
#define KSZ (256 * 17)

__global__ __launch_bounds__(SORT_T) void sort_kernel(const float* __restrict__ props,
                                                      const float* __restrict__ scores) {
    const int b = blockIdx.x;
    const int tid = threadIdx.x;
    __shared__ unsigned int K0[KSZ], K1[KSZ];
    __shared__ unsigned short P0[KSZ], P1[KSZ];
    __shared__ unsigned short Hs[16 * HP];
    __shared__ unsigned int sWT[4];
    __shared__ int s_cnt;
    if (tid == 0) s_cnt = 0;
    __syncthreads();

    int localc = 0;
    for (int n = tid; n < NPAD; n += SORT_T) {
        unsigned int k = 0xFFFFFFu;
        if (n < NBOX) {
            const float2 sc = *reinterpret_cast<const float2*>(scores + ((size_t)b * NBOX + n) * 2);
            const float4 p  = *reinterpret_cast<const float4*>(props  + ((size_t)b * NBOX + n) * 4);
            const float fg = sc.y;
            const float w = __fsub_rn(p.z, p.x);
            const float h = __fsub_rn(p.w, p.y);
            if ((fg > 0.5f) && (w >= 16.0f) && (h >= 16.0f)) {
                k = 0x3F800000u - __float_as_uint(fg);
                localc++;
            }
        }
        K0[KIDX(n)] = k;
        P0[KIDX(n)] = (unsigned short)n;
    }
    for (int off = 32; off > 0; off >>= 1) localc += __shfl_down(localc, off);
    if ((tid & 63) == 0) atomicAdd(&s_cnt, localc);

    unsigned int kr[EPT];
    unsigned short pr[EPT];

    for (int pass = 0; pass < 6; ++pass) {
        const int shift = pass * 4;
        const unsigned int*   ksrc = (pass & 1) ? K1 : K0;
        unsigned int*         kdst = (pass & 1) ? K0 : K1;
        const unsigned short* psrc = (pass & 1) ? P1 : P0;
        unsigned short*       pdst = (pass & 1) ? P0 : P1;

        for (int hh = tid; hh < (16 * HP) / 2; hh += SORT_T)
            reinterpret_cast<unsigned int*>(Hs)[hh] = 0;
        __syncthreads();

        #pragma unroll
        for (int e = 0; e < EPT; ++e) {
            kr[e] = ksrc[tid * 17 + e];
            pr[e] = psrc[tid * 17 + e];
        }
        #pragma unroll
        for (int e = 0; e < EPT; ++e) {
            const unsigned int d = (kr[e] >> shift) & 15u;
            Hs[d * HP + tid]++;
        }
        __syncthreads();

        {
            const int d  = tid >> 4;
            const int t0 = (tid & 15) * 16;
            unsigned short* row = &Hs[d * HP];
            unsigned int sum = 0;
            #pragma unroll
            for (int e = 0; e < 16; ++e) {
                const unsigned int v = row[t0 + e];
                row[t0 + e] = (unsigned short)sum;
                sum += v;
            }
            unsigned int x = sum;
            #pragma unroll
            for (int off = 1; off < 64; off <<= 1) {
                const unsigned int y = __shfl_up(x, off);
                if ((tid & 63) >= off) x += y;
            }
            const int wid = tid >> 6;
            if ((tid & 63) == 63) sWT[wid] = x;
            __syncthreads();
            unsigned int base = x - sum;
            for (int w = 0; w < wid; ++w) base += sWT[w];
            #pragma unroll
            for (int e = 0; e < 16; ++e) row[t0 + e] += (unsigned short)base;
        }
        __syncthreads();

        #pragma unroll
        for (int e = 0; e < EPT; ++e) {
            const unsigned int d = (kr[e] >> shift) & 15u;
            const unsigned int pos = Hs[d * HP + tid]++;
            kdst[KIDX(pos)] = kr[e];
            pdst[KIDX(pos)] = pr[e];
        }
        __syncthreads();
    }

    const int nv = s_cnt;
    if (tid == 0) g_nvalid[b] = nv;
    for (int p = tid; p < NPAD; p += SORT_T) {
        if (p < nv) {
            const int idx = P0[KIDX(p)];
            g_sorted[b][p] = *reinterpret_cast<const float4*>(props + ((size_t)b * NBOX + idx) * 4);
        }
    }
}

// ---------------------------------------------------------------------------
// Kernel 2: suppression bitmask rows (triangular) + 128-wide SB tile write.
// After the ballot loop, lane c holds word c of row i. For SB s = i>>7:
//   tileA[s][r] = word 2s   (columns [128s,128s+64));  zero for upper-half
//                 rows (all those j <= i), and lane 2s's myword is 0 there.
//   tileB[s][r] = word 2s+1 (columns [128s+64,128s+128)).
// ---------------------------------------------------------------------------
__global__ __launch_bounds__(64) void iou_kernel() {
    const int b = blockIdx.y;
    const int i = blockIdx.x;
    const int nv = g_nvalid[b];
    if (i >= nv) return;
    const int lane = threadIdx.x;
    const int c0 = i >> 6;
    const int W = (nv + 63) >> 6;

    const float4 bi = g_sorted[b][i];
    const float areai = __fmul_rn(__fsub_rn(bi.z, bi.x), __fsub_rn(bi.w, bi.y));

    u64 myword = 0ull;
    for (int c = c0; c < W; ++c) {
        const int j = (c << 6) + lane;
        bool pred = false;
        if (j < nv && j > i) {
            const float4 bj = g_sorted[b][j];
            const float areaj = __fmul_rn(__fsub_rn(bj.z, bj.x), __fsub_rn(bj.w, bj.y));
            const float xi1 = fmaxf(bi.x, bj.x);
            const float yi1 = fmaxf(bi.y, bj.y);
            const float xi2 = fminf(bi.z, bj.z);
            const float yi2 = fminf(bi.w, bj.w);
            const float iw = fmaxf(__fsub_rn(xi2, xi1), 0.0f);
            const float ih = fmaxf(__fsub_rn(yi2, yi1), 0.0f);
            const float inter = __fmul_rn(iw, ih);
            const float uni = __fsub_rn(__fadd_rn(areai, areaj), inter);
            pred = (inter / uni) >= 0.5f;
        }
        const u64 wd = __ballot(pred);
        if (lane == c) myword = wd;
    }
    g_sup[b][i][lane] = myword;

    const int sb = i >> 7;
    const int r  = i & 127;
    if (lane == 2 * sb)     g_tileA[b][sb][r] = myword;
    if (lane == 2 * sb + 1) g_tileB[b][sb][r] = myword;
}

// ---------------------------------------------------------------------------
// Kernel 3: greedy scan, one wave per batch, 128-row superblocks processed
// BANK-SEQUENTIALLY (rows 0-63 fully, then 64-127 — which IS ascending order):
//   bank0 rows: 2 readlanes each (A0=intra-bank word, A1=onto-bank1 word)
//   bank1 rows: 1 rdl64 each (their low word is provably zero)
// Tile columns live in 6 u64 regs, prefetched one SB ahead (coalesced).
// Cross-SB OR: R4-proven direct batched loads (32 named regs, ONE drain per
// SB — the single unavoidable MALL round trip). 14 serial steps vs R4's 28.
// ---------------------------------------------------------------------------
__device__ __forceinline__ int rdl(int v, int l) {
    return __builtin_amdgcn_readlane(v, l);
}
__device__ __forceinline__ unsigned int rdlu(unsigned int v, int l) {
    return (unsigned int)__builtin_amdgcn_readlane((int)v, l);
}
__device__ __forceinline__ u64 rdl64(u64 v, int l) {
    const unsigned lo = rdlu((unsigned)v, l);
    const unsigned hi = rdlu((unsigned)(v >> 32), l);
    return ((u64)hi << 32) | lo;
}
__device__ __forceinline__ u64 mask64(int n) {   // bits [0,n), clamped
    return (n >= 64) ? ~0ull : ((n <= 0) ? 0ull : ((1ull << n) - 1ull));
}

__global__ __launch_bounds__(64) void nms_kernel(float* __restrict__ out) {
    const int b = blockIdx.x;
    const int lane = threadIdx.x;
    int nv = g_nvalid[b];
    if (nv > NBOX) nv = NBOX;
    float4* outv = reinterpret_cast<float4*>(out) + (size_t)b * MAXK;
    const u64* supb = &g_sup[b][0][0];

    // zero-fill output up-front (off the critical chain)
    for (int s = lane; s < MAXK; s += 64)
        outv[s] = make_float4(0.0f, 0.0f, 0.0f, 0.0f);

    u64 removed = 0ull;                 // lane w holds removed word w
    int kept = 0;
    const int nsb = (nv + 127) >> 7;    // <= 32

    // prologue: SB 0 tile columns
    u64 A0 = g_tileA[b][0][lane];       // intra-bank0 word of row lane
    u64 A1 = g_tileB[b][0][lane];       // bank0-row onto bank1 word
    u64 B1 = g_tileB[b][0][64 + lane];  // intra-bank1 word of row 64+lane

    for (int s = 0; s < nsb && kept < MAXK; ++s) {
        const int base = s << 7;
        // prefetch next SB's tile columns (coalesced, consumed next iter;
        // tile arrays padded to NSB2+1 so s+1 is always in-bounds)
        const u64 NA0 = g_tileA[b][s + 1][lane];
        const u64 NA1 = g_tileB[b][s + 1][lane];
        const u64 NB1 = g_tileB[b][s + 1][64 + lane];

        // incoming suppression words for this SB (scalar)
        const u64 w0 = rdl64(removed, 2 * s);
        const u64 w1 = rdl64(removed, 2 * s + 1);
        const int rem = nv - base;
        u64 a0v = ~w0 & mask64(rem);
        u64 a1v = ~w1 & mask64(rem - 64);
        unsigned int al0_lo = (unsigned)__builtin_amdgcn_readfirstlane((int)(unsigned)a0v);
        unsigned int al0_hi = (unsigned)__builtin_amdgcn_readfirstlane((int)(unsigned)(a0v >> 32));
        unsigned int al1_lo = (unsigned)__builtin_amdgcn_readfirstlane((int)(unsigned)a1v);
        unsigned int al1_hi = (unsigned)__builtin_amdgcn_readfirstlane((int)(unsigned)(a1v >> 32));

        const unsigned int A0lo = (unsigned)A0, A0hi = (unsigned)(A0 >> 32);
        const unsigned int A1lo = (unsigned)A1, A1hi = (unsigned)(A1 >> 32);
        const unsigned int B1lo = (unsigned)B1, B1hi = (unsigned)(B1 >> 32);

        int m = 0;
        int myIdx0 = 0, myIdx1 = 0;     // lane t: t-th / (64+t)-th kept index
        const int cap = MAXK - kept;

        // (a) bank 0: rows base..base+63, ascending (2 readlane64 per kept)
        while ((al0_lo | al0_hi) != 0u && m < cap) {
            const int l = al0_lo ? __builtin_ctz(al0_lo) : 32 + __builtin_ctz(al0_hi);
            const unsigned int s0lo = rdlu(A0lo, l), s0hi = rdlu(A0hi, l);
            const unsigned int s1lo = rdlu(A1lo, l), s1hi = rdlu(A1hi, l);
            const u64 clr0 = (((u64)s0hi << 32) | s0lo) | (1ull << l);
            al0_lo &= ~(unsigned)clr0;
            al0_hi &= ~(unsigned)(clr0 >> 32);
            al1_lo &= ~s1lo;
            al1_hi &= ~s1hi;
            if (m < 64) { if (lane == m) myIdx0 = base + l; }
            else        { if (lane == m - 64) myIdx1 = base + l; }
            ++m;
        }
        // (b) bank 1: rows base+64..base+127, ascending (1 readlane64 per kept)
        while ((al1_lo | al1_hi) != 0u && m < cap) {
            const int l = al1_lo ? __builtin_ctz(al1_lo) : 32 + __builtin_ctz(al1_hi);
            const unsigned int t1lo = rdlu(B1lo, l), t1hi = rdlu(B1hi, l);
            const u64 clr1 = (((u64)t1hi << 32) | t1lo) | (1ull << l);
            al1_lo &= ~(unsigned)clr1;
            al1_hi &= ~(unsigned)(clr1 >> 32);
            if (m < 64) { if (lane == m) myIdx0 = base + 64 + l; }
            else        { if (lane == m - 64) myIdx1 = base + 64 + l; }
            ++m;
        }

        if (m > 0) {
            // (c) batched OR of kept rows' full suppression rows (direct from
            // L2/MALL — only m rows, 32 independent loads, ONE drain)
            if (kept + m < MAXK && s + 1 < nsb) {
                for (int t = 0; t < m; t += 32) {
#define LDW(j) u64 v##j; {                                                      \
                        int tt = t + j; if (tt >= m) tt = m - 1;                \
                        const int it = (tt < 64) ? rdl(myIdx0, tt)              \
                                                 : rdl(myIdx1, tt - 64);        \
                        v##j = supb[(size_t)it * WPR + lane];                   }
                    LDW(0)  LDW(1)  LDW(2)  LDW(3)  LDW(4)  LDW(5)  LDW(6)  LDW(7)
                    LDW(8)  LDW(9)  LDW(10) LDW(11) LDW(12) LDW(13) LDW(14) LDW(15)
                    LDW(16) LDW(17) LDW(18) LDW(19) LDW(20) LDW(21) LDW(22) LDW(23)
                    LDW(24) LDW(25) LDW(26) LDW(27) LDW(28) LDW(29) LDW(30) LDW(31)
#undef LDW
                    const u64 o0 = ((v0 | v1) | (v2 | v3)) | ((v4 | v5) | (v6 | v7));
                    const u64 o1 = ((v8 | v9) | (v10 | v11)) | ((v12 | v13) | (v14 | v15));
                    const u64 o2 = ((v16 | v17) | (v18 | v19)) | ((v20 | v21) | (v22 | v23));
                    const u64 o3 = ((v24 | v25) | (v26 | v27)) | ((v28 | v29) | (v30 | v31));
                    removed |= (o0 | o1) | (o2 | o3);
                }
            }
            // (d) emit this SB's outputs (off-chain)
            {
                const int m0 = (m < 64) ? m : 64;
                if (lane < m0) outv[kept + lane] = g_sorted[b][myIdx0];
                if (m > 64 && lane < m - 64) outv[kept + 64 + lane] = g_sorted[b][myIdx1];
            }
            kept += m;
        }
        A0 = NA0; A1 = NA1; B1 = NB1;
    }
}

extern "C" void kernel_launch(void* const* d_in, const int* in_sizes, int n_in,
                              void* d_out, int out_size, void* d_ws, size_t ws_size,
                              hipStream_t stream) {
    const float* props  = (const float*)d_in[0];   // (8,4000,4) f32
    const float* scores = (const float*)d_in[1];   // (8,4000,2) f32
    float* out = (float*)d_out;                    // (8,300,4) f32

    sort_kernel<<<BATCH, SORT_T, 0, stream>>>(props, scores);
    iou_kernel<<<dim3(NBOX, BATCH), 64, 0, stream>>>();
    nms_kernel<<<BATCH, 64, 0, stream>>>(out);
}

// Round 9
// 89.095 us; speedup vs baseline: 1.0625x; 1.0625x over previous
//
#include <hip/hip_runtime.h>

#define NBOX 4000
#define NPAD 4096
#define BATCH 8
#define WPR 64          // 64-bit words per suppression row
#define MAXK 300

typedef unsigned long long u64;

// Static device scratch (deterministic: everything consulted is rewritten
// every call; rows/bits >= nvalid are masked out before use).
__device__ u64 g_sup[BATCH][NPAD][WPR];            // ~16.8 MB full rows
__device__ u64 g_tile64[BATCH][64][64];            // word blk of row blk*64+r
__device__ u64 g_colT[BATCH][64][64];              // transposed diagonal blocks
__device__ float4 g_sorted[BATCH][NPAD];           // 512 KB
__device__ int g_nvalid[BATCH];

// ---------------------------------------------------------------------------
// Kernel 1: per-batch stable LSD radix sort (6 passes x 4 bits). (unchanged,
// proven bit-exact) Key k = 0x3F800000 - bits(fg): valid => fg > 0.5 => k in
// (0, 0x800000), fits 24 bits. Invalid/pad k = 0xFFFFFF sorts last. Stable
// blocked radix preserves original-index order for ties (jnp.argsort).
// ---------------------------------------------------------------------------
#define SORT_T 256
#define EPT 16
#define HP 264
#define KIDX(n) ((((n) >> 4) * 17) + ((n) & 15))
#define KSZ (256 * 17)

__global__ __launch_bounds__(SORT_T) void sort_kernel(const float* __restrict__ props,
                                                      const float* __restrict__ scores) {
    const int b = blockIdx.x;
    const int tid = threadIdx.x;
    __shared__ unsigned int K0[KSZ], K1[KSZ];
    __shared__ unsigned short P0[KSZ], P1[KSZ];
    __shared__ unsigned short Hs[16 * HP];
    __shared__ unsigned int sWT[4];
    __shared__ int s_cnt;
    if (tid == 0) s_cnt = 0;
    __syncthreads();

    int localc = 0;
    for (int n = tid; n < NPAD; n += SORT_T) {
        unsigned int k = 0xFFFFFFu;
        if (n < NBOX) {
            const float2 sc = *reinterpret_cast<const float2*>(scores + ((size_t)b * NBOX + n) * 2);
            const float4 p  = *reinterpret_cast<const float4*>(props  + ((size_t)b * NBOX + n) * 4);
            const float fg = sc.y;
            const float w = __fsub_rn(p.z, p.x);
            const float h = __fsub_rn(p.w, p.y);
            if ((fg > 0.5f) && (w >= 16.0f) && (h >= 16.0f)) {
                k = 0x3F800000u - __float_as_uint(fg);
                localc++;
            }
        }
        K0[KIDX(n)] = k;
        P0[KIDX(n)] = (unsigned short)n;
    }
    for (int off = 32; off > 0; off >>= 1) localc += __shfl_down(localc, off);
    if ((tid & 63) == 0) atomicAdd(&s_cnt, localc);

    unsigned int kr[EPT];
    unsigned short pr[EPT];

    for (int pass = 0; pass < 6; ++pass) {
        const int shift = pass * 4;
        const unsigned int*   ksrc = (pass & 1) ? K1 : K0;
        unsigned int*         kdst = (pass & 1) ? K0 : K1;
        const unsigned short* psrc = (pass & 1) ? P1 : P0;
        unsigned short*       pdst = (pass & 1) ? P0 : P1;

        for (int hh = tid; hh < (16 * HP) / 2; hh += SORT_T)
            reinterpret_cast<unsigned int*>(Hs)[hh] = 0;
        __syncthreads();

        #pragma unroll
        for (int e = 0; e < EPT; ++e) {
            kr[e] = ksrc[tid * 17 + e];
            pr[e] = psrc[tid * 17 + e];
        }
        #pragma unroll
        for (int e = 0; e < EPT; ++e) {
            const unsigned int d = (kr[e] >> shift) & 15u;
            Hs[d * HP + tid]++;
        }
        __syncthreads();

        {
            const int d  = tid >> 4;
            const int t0 = (tid & 15) * 16;
            unsigned short* row = &Hs[d * HP];
            unsigned int sum = 0;
            #pragma unroll
            for (int e = 0; e < 16; ++e) {
                const unsigned int v = row[t0 + e];
                row[t0 + e] = (unsigned short)sum;
                sum += v;
            }
            unsigned int x = sum;
            #pragma unroll
            for (int off = 1; off < 64; off <<= 1) {
                const unsigned int y = __shfl_up(x, off);
                if ((tid & 63) >= off) x += y;
            }
            const int wid = tid >> 6;
            if ((tid & 63) == 63) sWT[wid] = x;
            __syncthreads();
            unsigned int base = x - sum;
            for (int w = 0; w < wid; ++w) base += sWT[w];
            #pragma unroll
            for (int e = 0; e < 16; ++e) row[t0 + e] += (unsigned short)base;
        }
        __syncthreads();

        #pragma unroll
        for (int e = 0; e < EPT; ++e) {
            const unsigned int d = (kr[e] >> shift) & 15u;
            const unsigned int pos = Hs[d * HP + tid]++;
            kdst[KIDX(pos)] = kr[e];
            pdst[KIDX(pos)] = pr[e];
        }
        __syncthreads();
    }

    const int nv = s_cnt;
    if (tid == 0) g_nvalid[b] = nv;
    for (int p = tid; p < NPAD; p += SORT_T) {
        if (p < nv) {
            const int idx = P0[KIDX(p)];
            g_sorted[b][p] = *reinterpret_cast<const float4*>(props + ((size_t)b * NBOX + idx) * 4);
        }
    }
}

// ---------------------------------------------------------------------------
// Kernel 2: suppression bitmask rows (triangular) + diagonal-word tile write.
// g_sup stores nontemporally (streamed toward MALL, not left dirty in remote
// L2s) since the single consumer (nms) runs on a different XCD.
// ---------------------------------------------------------------------------
__global__ __launch_bounds__(64) void iou_kernel() {
    const int b = blockIdx.y;
    const int i = blockIdx.x;
    const int nv = g_nvalid[b];
    if (i >= nv) return;
    const int lane = threadIdx.x;
    const int c0 = i >> 6;
    const int W = (nv + 63) >> 6;

    const float4 bi = g_sorted[b][i];
    const float areai = __fmul_rn(__fsub_rn(bi.z, bi.x), __fsub_rn(bi.w, bi.y));

    u64 myword = 0ull;
    for (int c = c0; c < W; ++c) {
        const int j = (c << 6) + lane;
        bool pred = false;
        if (j < nv && j > i) {
            const float4 bj = g_sorted[b][j];
            const float areaj = __fmul_rn(__fsub_rn(bj.z, bj.x), __fsub_rn(bj.w, bj.y));
            const float xi1 = fmaxf(bi.x, bj.x);
            const float yi1 = fmaxf(bi.y, bj.y);
            const float xi2 = fminf(bi.z, bj.z);
            const float yi2 = fminf(bi.w, bj.w);
            const float iw = fmaxf(__fsub_rn(xi2, xi1), 0.0f);
            const float ih = fmaxf(__fsub_rn(yi2, yi1), 0.0f);
            const float inter = __fmul_rn(iw, ih);
            const float uni = __fsub_rn(__fadd_rn(areai, areaj), inter);
            pred = (inter / uni) >= 0.5f;
        }
        const u64 wd = __ballot(pred);
        if (lane == c) myword = wd;
    }
    __builtin_nontemporal_store(myword, &g_sup[b][i][lane]);
    if (lane == c0) g_tile64[b][c0][i & 63] = myword;
}

// ---------------------------------------------------------------------------
// Kernel 2b: transpose each 64x64 diagonal block. Lane j builds COLUMN j:
// bit r = M[base+r][base+j]. 64 broadcast loads (all lanes same address),
// fully parallel across 64x8 blocks — negligible time. Bits for rows >= nv
// are stale garbage but only consulted for kept rows (< nv), never reached.
// ---------------------------------------------------------------------------
__global__ __launch_bounds__(64) void colT_kernel() {
    const int b = blockIdx.y;
    const int blk = blockIdx.x;     // 0..63
    const int j = threadIdx.x;
    const u64* rw = &g_tile64[b][blk][0];
    u64 col = 0ull;
    #pragma unroll
    for (int r = 0; r < 64; ++r)
        col |= ((rw[r] >> j) & 1ull) << r;
    g_colT[b][blk][j] = col;
}

// ---------------------------------------------------------------------------
// Kernel 3: greedy scan, one wave per batch, BALLOT-GREEDY per 64-row block:
// lane j holds column j of the diagonal block (colT) and a 1-bit alive flag.
// Per kept row: k = ctz(__ballot(alive)) [uniform]; alive &= !((colT>>k)&1)
// && (lane!=k) — ALL LANE-LOCAL VALU, no readlane broadcast on the chain
// (~50 cy/row vs ~250 cy/row for the R4-R8 readlane greedy, the measured
// invariant floor). Cross-block OR: R4-proven batched loads (32 named regs,
// ONE drain per block — the single unavoidable MALL round trip).
// ---------------------------------------------------------------------------
__device__ __forceinline__ int rdl(int v, int l) {
    return __builtin_amdgcn_readlane(v, l);
}
__device__ __forceinline__ unsigned int rdlu(unsigned int v, int l) {
    return (unsigned int)__builtin_amdgcn_readlane((int)v, l);
}
__device__ __forceinline__ u64 rdl64(u64 v, int l) {
    const unsigned lo = rdlu((unsigned)v, l);
    const unsigned hi = rdlu((unsigned)(v >> 32), l);
    return ((u64)hi << 32) | lo;
}

__global__ __launch_bounds__(64) void nms_kernel(float* __restrict__ out) {
    const int b = blockIdx.x;
    const int lane = threadIdx.x;
    int nv = g_nvalid[b];
    if (nv > NBOX) nv = NBOX;
    float4* outv = reinterpret_cast<float4*>(out) + (size_t)b * MAXK;
    const u64* supb = &g_sup[b][0][0];

    // zero-fill output up-front (off the critical chain)
    for (int s = lane; s < MAXK; s += 64)
        outv[s] = make_float4(0.0f, 0.0f, 0.0f, 0.0f);

    u64 removed = 0ull;                 // lane w holds removed word w
    int kept = 0;
    const int nblk = (nv + 63) >> 6;    // <= 63

    u64 colT = g_colT[b][0][lane];      // column lane of diagonal block 0

    for (int blk = 0; blk < nblk && kept < MAXK; ++blk) {
        const int base = blk << 6;
        // prefetch next block's transposed column (blk+1 <= 63, in-bounds)
        const u64 colT_n = g_colT[b][blk + 1][lane];

        // incoming suppression word for this block (2 readlanes, once/block)
        const u64 wv = rdl64(removed, blk);

        // per-lane alive bit for row base+lane
        int alive = (int)((~wv >> lane) & 1ull) & (int)(base + lane < nv);

        int m = 0;
        int myIdx = 0;                  // lane t holds the t-th kept index
        const int cap = MAXK - kept;
        u64 bal = __ballot(alive != 0);
        while (bal != 0ull && m < cap) {
            const int k = __builtin_ctzll(bal);           // uniform
            if (lane == m) myIdx = base + k;
            alive &= (int)(~(colT >> k) & 1ull) & (int)(lane != k);
            ++m;
            bal = __ballot(alive != 0);
        }

        if (m > 0) {
            // batched OR of kept rows' full suppression rows (m <= 64 rows,
            // 32 independent nt loads per group, ONE drain per block)
            if (kept + m < MAXK && blk + 1 < nblk) {
                for (int t = 0; t < m; t += 32) {
#define LDW(j) u64 v##j; {                                                      \
                        int tt = t + j; if (tt >= m) tt = m - 1;                \
                        const int it = rdl(myIdx, tt);                          \
                        v##j = __builtin_nontemporal_load(                      \
                                   &supb[(size_t)it * WPR + lane]);             }
                    LDW(0)  LDW(1)  LDW(2)  LDW(3)  LDW(4)  LDW(5)  LDW(6)  LDW(7)
                    LDW(8)  LDW(9)  LDW(10) LDW(11) LDW(12) LDW(13) LDW(14) LDW(15)
                    LDW(16) LDW(17) LDW(18) LDW(19) LDW(20) LDW(21) LDW(22) LDW(23)
                    LDW(24) LDW(25) LDW(26) LDW(27) LDW(28) LDW(29) LDW(30) LDW(31)
#undef LDW
                    const u64 o0 = ((v0 | v1) | (v2 | v3)) | ((v4 | v5) | (v6 | v7));
                    const u64 o1 = ((v8 | v9) | (v10 | v11)) | ((v12 | v13) | (v14 | v15));
                    const u64 o2 = ((v16 | v17) | (v18 | v19)) | ((v20 | v21) | (v22 | v23));
                    const u64 o3 = ((v24 | v25) | (v26 | v27)) | ((v28 | v29) | (v30 | v31));
                    removed |= (o0 | o1) | (o2 | o3);
                }
            }
            // emit this block's outputs (off-chain; m <= 64 <= cap guard above)
            if (lane < m) outv[kept + lane] = g_sorted[b][myIdx];
            kept += m;
        }
        colT = colT_n;
    }
}

extern "C" void kernel_launch(void* const* d_in, const int* in_sizes, int n_in,
                              void* d_out, int out_size, void* d_ws, size_t ws_size,
                              hipStream_t stream) {
    const float* props  = (const float*)d_in[0];   // (8,4000,4) f32
    const float* scores = (const float*)d_in[1];   // (8,4000,2) f32
    float* out = (float*)d_out;                    // (8,300,4) f32

    sort_kernel<<<BATCH, SORT_T, 0, stream>>>(props, scores);
    iou_kernel<<<dim3(NBOX, BATCH), 64, 0, stream>>>();
    colT_kernel<<<dim3(64, BATCH), 64, 0, stream>>>();
    nms_kernel<<<BATCH, 64, 0, stream>>>(out);
}